// Round 15
// baseline (108.721 us; speedup 1.0000x reference)
//
#include <hip/hip_runtime.h>
#include <math.h>

#define HH 512
#define WW 512
#define NB 8
#define NN 256
#define KR 6
#define KS 13

// ---- compile-time 17-diagonal band of M = I - X + X^2 - X^3 + X^4,
//      X = STEPSZ*(ALPHA*D + BETA*D^2).  ||X|| <= 0.02 -> truncation ~1.6e-6.
//      Taps referencing out-of-chain nodes are EXACTLY zero (relied upon for
//      edge handling and ghost-junk annihilation).
struct MBand { float c[NN][17]; };

constexpr double Dd_c(int i, int j) {
    if (i < 0 || i >= NN || j < 0 || j >= NN) return 0.0;
    if (i == j) return (i == 0 || i == NN - 1) ? 1.0 : 2.0;
    int d = i - j;
    if (d == 1 || d == -1) return -1.0;
    return 0.0;
}

constexpr MBand make_mband() {
    MBand mb{};
    double xb[NN][5] = {};
    for (int n = 0; n < NN; ++n)
        for (int d = 0; d < 5; ++d) {
            int j = n + d - 2;
            double d2 = 0.0;
            for (int k = n - 1; k <= n + 1; ++k) d2 += Dd_c(n, k) * Dd_c(k, j);
            xb[n][d] = 0.1 * (0.01 * Dd_c(n, j) + 0.01 * d2);
        }
    for (int n = 0; n < NN; ++n) {
        double acc[17] = {};
        double cur[17] = {};
        acc[8] = 1.0; cur[8] = 1.0;
        double sign = -1.0;
        for (int k = 1; k <= 4; ++k) {
            double nxt[17] = {};
            int lo = -2 * k, hi = 2 * k;
            for (int tp = lo; tp <= hi; ++tp) {
                int j = n + tp;
                double s = 0.0;
                if (j >= 0 && j < NN) {
                    for (int t = tp - 2; t <= tp + 2; ++t) {
                        if (t < -8 || t > 8) continue;
                        int m = n + t;
                        if (m < 0 || m >= NN) continue;
                        s += cur[8 + t] * xb[m][(tp - t) + 2];
                    }
                }
                nxt[8 + tp] = s;
            }
            for (int q = 0; q < 17; ++q) { cur[q] = nxt[q]; acc[q] += sign * nxt[q]; }
            sign = -sign;
        }
        for (int q = 0; q < 17; ++q) mb.c[n][q] = (float)acc[q];
    }
    return mb;
}

__device__ __constant__ MBand d_mband = make_mband();

// ---- per-batch completion counters (module globals, loader zero-inits).
// Replay-safe: last snake block of each batch resets both to 0.
__device__ unsigned g_cnt[NB]  = {};
__device__ unsigned g_done[NB] = {};

// ========== fused conv + snake ==========
// 2048 blocks. Every block: conv one 32x32 tile of batch b = blockIdx&7, then
// release-increment g_cnt[b]. Blocks 0..63 additionally run one snake chunk
// (batch = blockIdx&7, chunk = blockIdx>>3) after spin-waiting for all 256
// conv increments of their batch. Producers never wait -> no deadlock under
// plain launch; 64 spinners poll 8 distinct lines at ~512-cycle intervals
// (R12's failure was 504 spinners on ONE line). Agent-scope release/acquire
// makes gimg visible via L3 (~450cyc) instead of a kernel boundary + HBM.
__global__ __launch_bounds__(256) void conv_snake_kernel(const float* __restrict__ pred,
                                                         const float* __restrict__ node_pos,
                                                         float2* __restrict__ gimg2,
                                                         float* __restrict__ pos_out,
                                                         float* __restrict__ out) {
    __shared__ float tin[44][44];
    __shared__ float midG[44][32];
    __shared__ float midD[44][32];

    const int b    = blockIdx.x & 7;      // XCD-local: batch b on XCD b
    const int tile = blockIdx.x >> 3;     // 256 tiles (16x16)
    const int ty0  = (tile >> 4) * 32;
    const int tx0  = (tile & 15) * 32;
    const int t    = threadIdx.x;

    if (blockIdx.x == 0 && t == 0) out[0] = 0.f;   // zero loss accumulator

    // ---------------- conv phase ----------------
    {
        float g[KS], dg[KS];
        float s = 0.f;
#pragma unroll
        for (int i = 0; i < KS; ++i) {
            float x = (float)(i - KR);
            g[i] = expf(-x * x / 8.f);  // std=2 -> 2*std^2 = 8
            s += g[i];
        }
#pragma unroll
        for (int i = 0; i < KS; ++i) {
            g[i] /= s;
            dg[i] = (-(float)(i - KR) / 4.f) * g[i];
        }

        const float* img = pred + (size_t)b * HH * WW;

        for (int idx = t; idx < 44 * 44; idx += 256) {
            int ly = idx / 44, lx = idx % 44;
            int gy = ty0 + ly - KR, gx = tx0 + lx - KR;
            float v = 0.f;
            if (gy >= 0 && gy < HH && gx >= 0 && gx < WW) v = img[gy * WW + gx];
            tin[ly][lx] = v;
        }
        __syncthreads();

        for (int idx = t; idx < 44 * 32; idx += 256) {
            int ly = idx / 32, ox = idx % 32;
            float aG = 0.f, aD = 0.f;
#pragma unroll
            for (int k = 0; k < KS; ++k) {
                float v = tin[ly][ox + k];
                aG += v * g[k];
                aD += v * dg[k];
            }
            midG[ly][ox] = aG;
            midD[ly][ox] = aD;
        }
        __syncthreads();

        float2* outp = gimg2 + (size_t)b * HH * WW;
        for (int idx = t; idx < 32 * 32; idx += 256) {
            int oy = idx / 32, ox = idx % 32;
            float a0 = 0.f, a1 = 0.f;
#pragma unroll
            for (int k = 0; k < KS; ++k) {
                a0 += midG[oy + k][ox] * dg[k];
                a1 += midD[oy + k][ox] * g[k];
            }
            outp[(ty0 + oy) * WW + (tx0 + ox)] = make_float2(10.f * a0, 10.f * a1);
        }
    }

    __syncthreads();   // all tile stores issued
    if (t == 0)
        __hip_atomic_fetch_add(&g_cnt[b], 1u, __ATOMIC_RELEASE,
                               __HIP_MEMORY_SCOPE_AGENT);

    if (blockIdx.x >= 64) return;   // producers exit

    // ---------------- snake tail (blocks 0..63) ----------------
    // batch = b, chunk = tile (0..7): owns nodes 32*chunk..32*chunk+31,
    // simulates a 64-node window (8 lower / 24 upper ghosts), 1 node/lane.
    if (t == 0) {
        while (__hip_atomic_load(&g_cnt[b], __ATOMIC_RELAXED,
                                 __HIP_MEMORY_SCOPE_AGENT) < 256u)
            __builtin_amdgcn_s_sleep(8);
        (void)__hip_atomic_load(&g_cnt[b], __ATOMIC_ACQUIRE,
                                __HIP_MEMORY_SCOPE_AGENT);
    }
    __syncthreads();

    if (t < 64) {
        const int chunk = tile;
        const int l = t;
        const int nidx = chunk * 32 - 8 + l;                 // simulated chain index
        const int cidx = min(max(nidx, 0), NN - 1);          // clamped (dup at ends)

        const float2* gp = gimg2 + (size_t)b * HH * WW;

        float2 pp = ((const float2*)node_pos)[b * NN + cidx];
        float p0 = pp.x, p1 = pp.y;

        float mbc[17];
#pragma unroll
        for (int k = 0; k < 17; ++k) mbc[k] = d_mband.c[cidx][k];

        for (int step = 0; step < 20; ++step) {
            float r = fminf(fmaxf(p0, 0.f), (float)(HH - 1));
            float c = fminf(fmaxf(p1, 0.f), (float)(WW - 1));
            float rf = floorf(r), cf = floorf(c);
            int r0 = (int)rf, c0 = (int)cf;
            int r1 = min(r0 + 1, HH - 1), c1 = min(c0 + 1, WW - 1);
            float fr = r - rf, fc = c - cf;
            float2 v00 = gp[r0 * WW + c0];
            float2 v01 = gp[r0 * WW + c1];
            float2 v10 = gp[r1 * WW + c0];
            float2 v11 = gp[r1 * WW + c1];
            float w00 = (1.f - fr) * (1.f - fc), w01 = (1.f - fr) * fc;
            float w10 = fr * (1.f - fc),         w11 = fr * fc;
            float q0 = p0 + 0.1f * (w00 * v00.x + w01 * v01.x + w10 * v10.x + w11 * v11.x);
            float q1 = p1 + 0.1f * (w00 * v00.y + w01 * v01.y + w10 * v10.y + w11 * v11.y);

            // 17-tap band dot via lane shuffles (out-of-chain taps: coeff == 0)
            float a0 = mbc[8] * q0;
            float a1 = mbc[8] * q1;
#pragma unroll
            for (int d = 1; d <= 8; ++d) {
                float u0 = __shfl_up(q0, d),   u1 = __shfl_up(q1, d);
                float w0 = __shfl_down(q0, d), w1 = __shfl_down(q1, d);
                a0 += mbc[8 - d] * u0 + mbc[8 + d] * w0;
                a1 += mbc[8 - d] * u1 + mbc[8 + d] * w1;
            }
            p0 = fminf(fmaxf(a0, 0.f), (float)(HH - 1));
            p1 = fminf(fmaxf(a1, 0.f), (float)(WW - 1));
        }

        if (l >= 8 && l < 40)   // own nodes only
            ((float2*)pos_out)[b * NN + nidx] = make_float2(p0, p1);
    }

    __syncthreads();
    if (t == 0) {   // counter hygiene for the next (stream-ordered) launch
        unsigned d = __hip_atomic_fetch_add(&g_done[b], 1u, __ATOMIC_ACQ_REL,
                                            __HIP_MEMORY_SCOPE_AGENT);
        if (d == 7u) {
            __hip_atomic_store(&g_cnt[b], 0u, __ATOMIC_RELAXED,
                               __HIP_MEMORY_SCOPE_AGENT);
            __hip_atomic_store(&g_done[b], 0u, __ATOMIC_RELAXED,
                               __HIP_MEMORY_SCOPE_AGENT);
        }
    }
}

// ---------------- render distance map + MSE loss (tile-binned) ----------------
__global__ __launch_bounds__(256) void render_loss_kernel(const float* __restrict__ pred,
                                                          const float* __restrict__ pos,
                                                          const float* __restrict__ widths,
                                                          float* __restrict__ out) {
    __shared__ float sl0[NN], sl1[NN], slw[NN];
    __shared__ int cnt;
    __shared__ float wred[4];

    const int b    = blockIdx.x & 7;         // XCD-local: batch b tiles on XCD b
    const int tile = blockIdx.x >> 3;        // 256 tiles (16x16) per batch
    const int ty0  = (tile >> 4) * 32;
    const int tx0  = (tile & 15) * 32;
    const int t    = threadIdx.x;

    if (t == 0) cnt = 0;
    __syncthreads();

    {   // node t relevance test against dilated tile box
        float p0 = pos[(b * NN + t) * 2 + 0];
        float p1 = pos[(b * NN + t) * 2 + 1];
        float w  = widths[b * NN + t];
        float dy = fmaxf(fmaxf((float)ty0 - p0, p0 - (float)(ty0 + 31)), 0.f);
        float dx = fmaxf(fmaxf((float)tx0 - p1, p1 - (float)(tx0 + 31)), 0.f);
        float rr = 15.f + w;
        if (dy * dy + dx * dx <= rr * rr) {
            int i = atomicAdd(&cnt, 1);
            sl0[i] = p0; sl1[i] = p1; slw[i] = w;
        }
    }
    __syncthreads();
    const int c = cnt;

    // 4 contiguous pixels: row = t>>3, cols = (t&7)*4 ..+3
    const int oy = t >> 3;
    const int ox = (t & 7) * 4;
    const float fy = (float)(ty0 + oy);
    const float fx = (float)(tx0 + ox);

    float dm0 = 15.f, dm1 = 15.f, dm2 = 15.f, dm3 = 15.f;
    for (int j = 0; j < c; ++j) {
        float dy  = fy - sl0[j];
        float dy2 = dy * dy;
        float w   = slw[j];
        float dx  = fx - sl1[j];
        dm0 = fminf(dm0, __builtin_amdgcn_sqrtf(dy2 + dx * dx) - w);
        dx += 1.f;
        dm1 = fminf(dm1, __builtin_amdgcn_sqrtf(dy2 + dx * dx) - w);
        dx += 1.f;
        dm2 = fminf(dm2, __builtin_amdgcn_sqrtf(dy2 + dx * dx) - w);
        dx += 1.f;
        dm3 = fminf(dm3, __builtin_amdgcn_sqrtf(dy2 + dx * dx) - w);
    }
    dm0 = fminf(fmaxf(dm0, 0.f), 15.f);
    dm1 = fminf(fmaxf(dm1, 0.f), 15.f);
    dm2 = fminf(fmaxf(dm2, 0.f), 15.f);
    dm3 = fminf(fmaxf(dm3, 0.f), 15.f);

    const float4 pv = *(const float4*)(pred + (size_t)b * HH * WW
                                       + (ty0 + oy) * WW + (tx0 + ox));
    float e0 = pv.x - dm0, e1 = pv.y - dm1, e2 = pv.z - dm2, e3 = pv.w - dm3;
    float acc = (e0 * e0 + e1 * e1 + e2 * e2 + e3 * e3)
              * (1.0f / (float)(NB * HH * WW));

    // wave reduce (64 lanes) then 4 partials -> one atomic
#pragma unroll
    for (int m = 1; m < 64; m <<= 1) acc += __shfl_xor(acc, m);
    if ((t & 63) == 0) wred[t >> 6] = acc;
    __syncthreads();
    if (t == 0) atomicAdd(out, wred[0] + wred[1] + wred[2] + wred[3]);
}

extern "C" void kernel_launch(void* const* d_in, const int* in_sizes, int n_in,
                              void* d_out, int out_size, void* d_ws, size_t ws_size,
                              hipStream_t stream) {
    const float* pred     = (const float*)d_in[0];  // [8,1,512,512]
    const float* node_pos = (const float*)d_in[1];  // [8,256,2]
    const float* widths   = (const float*)d_in[2];  // [8,256]
    float* out = (float*)d_out;

    float2* gimg2  = (float2*)d_ws;                           // [8][512][512] float2 = 16 MB
    float* pos_out = (float*)d_ws + (size_t)NB * 2 * HH * WW; // [8][256][2]

    conv_snake_kernel<<<NB * 256, 256, 0, stream>>>(pred, node_pos,
                                                    gimg2, pos_out, out);

    render_loss_kernel<<<NB * 256, 256, 0, stream>>>(pred, pos_out, widths, out);
}

// Round 16
// 54.261 us; speedup vs baseline: 2.0037x; 2.0037x over previous
//
#include <hip/hip_runtime.h>
#include <hip/hip_bf16.h>
#include <math.h>

#define HH 512
#define WW 512
#define NB 8
#define NN 256
#define KR 6
#define KS 13

// ---- compile-time 17-diagonal band of M = I - X + X^2 - X^3 + X^4,
//      X = STEPSZ*(ALPHA*D + BETA*D^2).  ||X|| <= 0.02 -> truncation ~1.6e-6.
//      Taps referencing out-of-chain nodes are EXACTLY zero (relied upon for
//      edge handling and ghost-junk annihilation).
struct MBand { float c[NN][17]; };

constexpr double Dd_c(int i, int j) {
    if (i < 0 || i >= NN || j < 0 || j >= NN) return 0.0;
    if (i == j) return (i == 0 || i == NN - 1) ? 1.0 : 2.0;
    int d = i - j;
    if (d == 1 || d == -1) return -1.0;
    return 0.0;
}

constexpr MBand make_mband() {
    MBand mb{};
    double xb[NN][5] = {};
    for (int n = 0; n < NN; ++n)
        for (int d = 0; d < 5; ++d) {
            int j = n + d - 2;
            double d2 = 0.0;
            for (int k = n - 1; k <= n + 1; ++k) d2 += Dd_c(n, k) * Dd_c(k, j);
            xb[n][d] = 0.1 * (0.01 * Dd_c(n, j) + 0.01 * d2);
        }
    for (int n = 0; n < NN; ++n) {
        double acc[17] = {};
        double cur[17] = {};
        acc[8] = 1.0; cur[8] = 1.0;
        double sign = -1.0;
        for (int k = 1; k <= 4; ++k) {
            double nxt[17] = {};
            int lo = -2 * k, hi = 2 * k;
            for (int tp = lo; tp <= hi; ++tp) {
                int j = n + tp;
                double s = 0.0;
                if (j >= 0 && j < NN) {
                    for (int t = tp - 2; t <= tp + 2; ++t) {
                        if (t < -8 || t > 8) continue;
                        int m = n + t;
                        if (m < 0 || m >= NN) continue;
                        s += cur[8 + t] * xb[m][(tp - t) + 2];
                    }
                }
                nxt[8 + tp] = s;
            }
            for (int q = 0; q < 17; ++q) { cur[q] = nxt[q]; acc[q] += sign * nxt[q]; }
            sign = -sign;
        }
        for (int q = 0; q < 17; ++q) mb.c[n][q] = (float)acc[q];
    }
    return mb;
}

__device__ __constant__ MBand d_mband = make_mband();

// gimg pixel: both gradient channels packed bf16 (4 B). ~0.4% rel error ->
// ~0.04 px total position drift over 20 steps, ~70x below the 2.86 threshold.
union GPix { unsigned u; struct { __hip_bfloat16 x, y; } h; };

// ---------------- conv: separable 13x13 Gaussian-derivative, x10 ----------------
// Also zeroes out[0] (block 0) so no separate memset dispatch is needed.
__global__ __launch_bounds__(256) void conv_kernel(const float* __restrict__ pred,
                                                   unsigned* __restrict__ gimg,
                                                   float* __restrict__ out) {
    __shared__ float tin[44][44];
    __shared__ float midG[44][32];
    __shared__ float midD[44][32];

    const int b    = blockIdx.x & 7;      // XCD-local: batch b tiles on XCD b
    const int tile = blockIdx.x >> 3;     // 256 tiles (16x16)
    const int ty0  = (tile >> 4) * 32;
    const int tx0  = (tile & 15) * 32;
    const int t    = threadIdx.x;

    if (blockIdx.x == 0 && t == 0) out[0] = 0.f;

    float g[KS], dg[KS];
    float s = 0.f;
#pragma unroll
    for (int i = 0; i < KS; ++i) {
        float x = (float)(i - KR);
        g[i] = expf(-x * x / 8.f);  // std=2 -> 2*std^2 = 8
        s += g[i];
    }
#pragma unroll
    for (int i = 0; i < KS; ++i) {
        g[i] /= s;
        dg[i] = (-(float)(i - KR) / 4.f) * g[i];
    }

    const float* img = pred + (size_t)b * HH * WW;

    for (int idx = t; idx < 44 * 44; idx += 256) {
        int ly = idx / 44, lx = idx % 44;
        int gy = ty0 + ly - KR, gx = tx0 + lx - KR;
        float v = 0.f;
        if (gy >= 0 && gy < HH && gx >= 0 && gx < WW) v = img[gy * WW + gx];
        tin[ly][lx] = v;
    }
    __syncthreads();

    for (int idx = t; idx < 44 * 32; idx += 256) {
        int ly = idx / 32, ox = idx % 32;
        float aG = 0.f, aD = 0.f;
#pragma unroll
        for (int k = 0; k < KS; ++k) {
            float v = tin[ly][ox + k];
            aG += v * g[k];
            aD += v * dg[k];
        }
        midG[ly][ox] = aG;
        midD[ly][ox] = aD;
    }
    __syncthreads();

    unsigned* outp = gimg + (size_t)b * HH * WW;
    for (int idx = t; idx < 32 * 32; idx += 256) {
        int oy = idx / 32, ox = idx % 32;
        float a0 = 0.f, a1 = 0.f;
#pragma unroll
        for (int k = 0; k < KS; ++k) {
            a0 += midG[oy + k][ox] * dg[k];
            a1 += midD[oy + k][ox] * g[k];
        }
        GPix p;
        p.h.x = __float2bfloat16(10.f * a0);
        p.h.y = __float2bfloat16(10.f * a1);
        outp[(ty0 + oy) * WW + (tx0 + ox)] = p.u;
    }
}

// ---------------- snake: ghost-node domain decomposition ----------------
// 64 blocks = 8 batches x 8 chunks; each 1-wave block simulates a 64-node
// window (lane = one node): own nodes 32 (lanes 8..39), ghosts 8 below /
// 24 above. No inter-block sync for all 20 steps: band coefficients decay
// ~5e-3 per node-hop, so sim-edge error crossing the >=8-node ghost region
// into the owned nodes is <1e-13 px over 20 steps. True chain ends exact
// (out-of-chain taps have exactly-zero coefficients, annihilating the
// duplicated-lane junk every step). 8x the TCP miss slots vs 1 block/batch.
__global__ __launch_bounds__(64, 1) void snake_kernel(const unsigned* __restrict__ gimg,
                                                      const float* __restrict__ node_pos,
                                                      float* __restrict__ pos_out) {
    const int batch = blockIdx.x & 7;     // XCD-local: batch b chunks on XCD b
    const int chunk = blockIdx.x >> 3;    // 0..7, owns nodes 32*chunk..32*chunk+31
    const int l = threadIdx.x;
    const int nidx = chunk * 32 - 8 + l;                 // simulated chain index
    const int cidx = min(max(nidx, 0), NN - 1);          // clamped (dup at ends)

    const unsigned* gp = gimg + (size_t)batch * HH * WW;

    float2 pp = ((const float2*)node_pos)[batch * NN + cidx];
    float p0 = pp.x, p1 = pp.y;

    float mbc[17];
#pragma unroll
    for (int t = 0; t < 17; ++t) mbc[t] = d_mband.c[cidx][t];

    for (int step = 0; step < 20; ++step) {
        // bilerp force at (p0,p1) from packed-bf16 gradient image
        float r = fminf(fmaxf(p0, 0.f), (float)(HH - 1));
        float c = fminf(fmaxf(p1, 0.f), (float)(WW - 1));
        float rf = floorf(r), cf = floorf(c);
        int r0 = (int)rf, c0 = (int)cf;
        int r1 = min(r0 + 1, HH - 1), c1 = min(c0 + 1, WW - 1);
        float fr = r - rf, fc = c - cf;
        GPix v00, v01, v10, v11;
        v00.u = gp[r0 * WW + c0];
        v01.u = gp[r0 * WW + c1];
        v10.u = gp[r1 * WW + c0];
        v11.u = gp[r1 * WW + c1];
        float w00 = (1.f - fr) * (1.f - fc), w01 = (1.f - fr) * fc;
        float w10 = fr * (1.f - fc),         w11 = fr * fc;
        float f0 = w00 * __bfloat162float(v00.h.x) + w01 * __bfloat162float(v01.h.x)
                 + w10 * __bfloat162float(v10.h.x) + w11 * __bfloat162float(v11.h.x);
        float f1 = w00 * __bfloat162float(v00.h.y) + w01 * __bfloat162float(v01.h.y)
                 + w10 * __bfloat162float(v10.h.y) + w11 * __bfloat162float(v11.h.y);
        float q0 = p0 + 0.1f * f0;
        float q1 = p1 + 0.1f * f1;

        // 17-tap band dot via lane shuffles (out-of-chain taps: coeff == 0)
        float a0 = mbc[8] * q0;
        float a1 = mbc[8] * q1;
#pragma unroll
        for (int d = 1; d <= 8; ++d) {
            float u0 = __shfl_up(q0, d),   u1 = __shfl_up(q1, d);
            float w0 = __shfl_down(q0, d), w1 = __shfl_down(q1, d);
            a0 += mbc[8 - d] * u0 + mbc[8 + d] * w0;
            a1 += mbc[8 - d] * u1 + mbc[8 + d] * w1;
        }
        p0 = fminf(fmaxf(a0, 0.f), (float)(HH - 1));
        p1 = fminf(fmaxf(a1, 0.f), (float)(WW - 1));
    }

    if (l >= 8 && l < 40)   // own nodes only
        ((float2*)pos_out)[batch * NN + nidx] = make_float2(p0, p1);
}

// ---------------- render distance map + MSE loss (tile-binned) ----------------
__global__ __launch_bounds__(256) void render_loss_kernel(const float* __restrict__ pred,
                                                          const float* __restrict__ pos,
                                                          const float* __restrict__ widths,
                                                          float* __restrict__ out) {
    __shared__ float sl0[NN], sl1[NN], slw[NN];
    __shared__ int cnt;
    __shared__ float wred[4];

    const int b    = blockIdx.x & 7;         // XCD-local: batch b tiles on XCD b
    const int tile = blockIdx.x >> 3;        // 256 tiles (16x16) per batch
    const int ty0  = (tile >> 4) * 32;
    const int tx0  = (tile & 15) * 32;
    const int t    = threadIdx.x;

    if (t == 0) cnt = 0;
    __syncthreads();

    {   // node t relevance test against dilated tile box
        float p0 = pos[(b * NN + t) * 2 + 0];
        float p1 = pos[(b * NN + t) * 2 + 1];
        float w  = widths[b * NN + t];
        float dy = fmaxf(fmaxf((float)ty0 - p0, p0 - (float)(ty0 + 31)), 0.f);
        float dx = fmaxf(fmaxf((float)tx0 - p1, p1 - (float)(tx0 + 31)), 0.f);
        float rr = 15.f + w;
        if (dy * dy + dx * dx <= rr * rr) {
            int i = atomicAdd(&cnt, 1);
            sl0[i] = p0; sl1[i] = p1; slw[i] = w;
        }
    }
    __syncthreads();
    const int c = cnt;

    // 4 contiguous pixels: row = t>>3, cols = (t&7)*4 ..+3
    const int oy = t >> 3;
    const int ox = (t & 7) * 4;
    const float fy = (float)(ty0 + oy);
    const float fx = (float)(tx0 + ox);

    float dm0 = 15.f, dm1 = 15.f, dm2 = 15.f, dm3 = 15.f;
    for (int j = 0; j < c; ++j) {
        float dy  = fy - sl0[j];
        float dy2 = dy * dy;
        float w   = slw[j];
        float dx  = fx - sl1[j];
        dm0 = fminf(dm0, __builtin_amdgcn_sqrtf(dy2 + dx * dx) - w);
        dx += 1.f;
        dm1 = fminf(dm1, __builtin_amdgcn_sqrtf(dy2 + dx * dx) - w);
        dx += 1.f;
        dm2 = fminf(dm2, __builtin_amdgcn_sqrtf(dy2 + dx * dx) - w);
        dx += 1.f;
        dm3 = fminf(dm3, __builtin_amdgcn_sqrtf(dy2 + dx * dx) - w);
    }
    dm0 = fminf(fmaxf(dm0, 0.f), 15.f);
    dm1 = fminf(fmaxf(dm1, 0.f), 15.f);
    dm2 = fminf(fmaxf(dm2, 0.f), 15.f);
    dm3 = fminf(fmaxf(dm3, 0.f), 15.f);

    const float4 pv = *(const float4*)(pred + (size_t)b * HH * WW
                                       + (ty0 + oy) * WW + (tx0 + ox));
    float e0 = pv.x - dm0, e1 = pv.y - dm1, e2 = pv.z - dm2, e3 = pv.w - dm3;
    float acc = (e0 * e0 + e1 * e1 + e2 * e2 + e3 * e3)
              * (1.0f / (float)(NB * HH * WW));

    // wave reduce (64 lanes) then 4 partials -> one atomic
#pragma unroll
    for (int m = 1; m < 64; m <<= 1) acc += __shfl_xor(acc, m);
    if ((t & 63) == 0) wred[t >> 6] = acc;
    __syncthreads();
    if (t == 0) atomicAdd(out, wred[0] + wred[1] + wred[2] + wred[3]);
}

extern "C" void kernel_launch(void* const* d_in, const int* in_sizes, int n_in,
                              void* d_out, int out_size, void* d_ws, size_t ws_size,
                              hipStream_t stream) {
    const float* pred     = (const float*)d_in[0];  // [8,1,512,512]
    const float* node_pos = (const float*)d_in[1];  // [8,256,2]
    const float* widths   = (const float*)d_in[2];  // [8,256]
    float* out = (float*)d_out;

    unsigned* gimg = (unsigned*)d_ws;                         // [8][512][512] bf16x2 = 8 MB
    float* pos_out = (float*)d_ws + (size_t)NB * HH * WW;     // [8][256][2]

    conv_kernel<<<NB * 256, 256, 0, stream>>>(pred, gimg, out);

    snake_kernel<<<NB * 8, 64, 0, stream>>>(gimg, node_pos, pos_out);

    render_loss_kernel<<<NB * 256, 256, 0, stream>>>(pred, pos_out, widths, out);
}